// Round 1
// baseline (938.896 us; speedup 1.0000x reference)
//
#include <hip/hip_runtime.h>
#include <math.h>

#define N_DFT    512
#define N_HOP    256
#define N_FILTER 257
#define L_IN     262144
#define N_FRAME  1024
#define PAD_L    128
#define AMIN     1e-10f
#define DRANGE   80.0f
#define TF       8            // frames per block
#define NTHREADS 320          // 5 waves; f = tid for tid < 257

// d_ws[0..3]: uint bit-pattern of global max power (non-negative float -> uint compare == float compare)
__global__ void init_ws_kernel(unsigned* ws) { ws[0] = 0u; }

__global__ __launch_bounds__(NTHREADS) void spec_power_kernel(
    const float* __restrict__ x,
    const float* __restrict__ kr,
    const float* __restrict__ ki,
    float* __restrict__ out,
    unsigned* __restrict__ ws_max)
{
    __shared__ float buf[TF * N_HOP + N_HOP];   // 2304 floats = 9.2 KB
    __shared__ float wmax[NTHREADS / 64];

    const int blk = blockIdx.x;                 // 8192 blocks
    const int bc  = blk / (N_FRAME / TF);       // 0..63
    const int t0  = (blk % (N_FRAME / TF)) * TF;
    const int b   = bc >> 1;
    const int c   = bc & 1;

    const float* xc = x + (size_t)bc * L_IN;
    const int base = t0 * N_HOP - PAD_L;        // frame t0 sample 0 in x coords

    // Stage 8 overlapping frames = 2304 contiguous padded samples
    for (int s = threadIdx.x; s < TF * N_HOP + N_HOP; s += NTHREADS) {
        const int i = base + s;
        buf[s] = (i >= 0 && i < L_IN) ? xc[i] : 0.0f;
    }
    __syncthreads();

    const int f = threadIdx.x;
    float pmax = 0.0f;

    if (f < N_FILTER) {
        float re[TF], im[TF];
        #pragma unroll
        for (int j = 0; j < TF; ++j) { re[j] = 0.0f; im[j] = 0.0f; }

        #pragma unroll 2
        for (int d = 0; d < N_DFT; d += 4) {
            // weights: (d, f) layout -> coalesced across threads, L2-resident
            const float wr0 = kr[(d + 0) * N_FILTER + f];
            const float wr1 = kr[(d + 1) * N_FILTER + f];
            const float wr2 = kr[(d + 2) * N_FILTER + f];
            const float wr3 = kr[(d + 3) * N_FILTER + f];
            const float wi0 = ki[(d + 0) * N_FILTER + f];
            const float wi1 = ki[(d + 1) * N_FILTER + f];
            const float wi2 = ki[(d + 2) * N_FILTER + f];
            const float wi3 = ki[(d + 3) * N_FILTER + f];
            #pragma unroll
            for (int j = 0; j < TF; ++j) {
                const float4 fv = *(const float4*)&buf[j * N_HOP + d]; // LDS broadcast
                re[j] += fv.x * wr0 + fv.y * wr1 + fv.z * wr2 + fv.w * wr3;
                im[j] += fv.x * wi0 + fv.y * wi1 + fv.z * wi2 + fv.w * wi3;
            }
        }

        #pragma unroll
        for (int j = 0; j < TF; ++j) {
            float p = re[j] * re[j] + im[j] * im[j];
            p = fmaxf(p, AMIN);
            pmax = fmaxf(pmax, p);
            // out[b][f][t][c], t = t0 + j
            out[(((size_t)b * N_FILTER + f) * N_FRAME + (t0 + j)) * 2 + c] = p;
        }
    }

    // block max reduction -> one atomic
    #pragma unroll
    for (int off = 32; off > 0; off >>= 1)
        pmax = fmaxf(pmax, __shfl_down(pmax, off, 64));
    if ((threadIdx.x & 63) == 0) wmax[threadIdx.x >> 6] = pmax;
    __syncthreads();
    if (threadIdx.x == 0) {
        float m = wmax[0];
        #pragma unroll
        for (int w = 1; w < NTHREADS / 64; ++w) m = fmaxf(m, wmax[w]);
        atomicMax(ws_max, __float_as_uint(m));
    }
}

__global__ __launch_bounds__(256) void finalize_kernel(
    float* __restrict__ out,
    const unsigned* __restrict__ ws_max,
    int n4)
{
    const int i = blockIdx.x * 256 + threadIdx.x;
    if (i >= n4) return;
    const float mlog = 10.0f * log10f(__uint_as_float(*ws_max));
    float4 p = ((const float4*)out)[i];
    float4 v;
    v.x = fmaxf(10.0f * log10f(p.x) - mlog, -DRANGE);
    v.y = fmaxf(10.0f * log10f(p.y) - mlog, -DRANGE);
    v.z = fmaxf(10.0f * log10f(p.z) - mlog, -DRANGE);
    v.w = fmaxf(10.0f * log10f(p.w) - mlog, -DRANGE);
    ((float4*)out)[i] = v;
}

extern "C" void kernel_launch(void* const* d_in, const int* in_sizes, int n_in,
                              void* d_out, int out_size, void* d_ws, size_t ws_size,
                              hipStream_t stream) {
    const float* x  = (const float*)d_in[0];
    const float* kr = (const float*)d_in[1];
    const float* ki = (const float*)d_in[2];
    float* out      = (float*)d_out;
    unsigned* wsm   = (unsigned*)d_ws;

    init_ws_kernel<<<1, 1, 0, stream>>>(wsm);

    const int nblocks = (32 * 2) * (N_FRAME / TF);   // 8192
    spec_power_kernel<<<nblocks, NTHREADS, 0, stream>>>(x, kr, ki, out, wsm);

    const int n4 = out_size / 4;                     // out_size = 32*257*1024*2
    finalize_kernel<<<(n4 + 255) / 256, 256, 0, stream>>>(out, wsm, n4);
}

// Round 2
// 298.776 us; speedup vs baseline: 3.1425x; 3.1425x over previous
//
#include <hip/hip_runtime.h>
#include <math.h>

#define L_IN     262144
#define N_FRAME  1024
#define AMIN     1e-10f
#define DRANGE   80.0f
#define TFRM     16              // frames per block
#define UNITS_CH 544             // (16*256+256)/8 16B-units per channel
#define WS_W256_OFF 64
#define WS_HI_OFF   4096
#define WS_HALF     524288       // bytes per W array (32 frags *16 ks *64 lanes *16B)

typedef short bf16x8 __attribute__((ext_vector_type(8)));
typedef float f32x4  __attribute__((ext_vector_type(4)));

__device__ __forceinline__ short f2bf(float f) {           // fp32 -> bf16 RNE
    unsigned u = __float_as_uint(f);
    u = (u + 0x7FFFu + ((u >> 16) & 1u)) >> 16;
    return (short)u;
}
__device__ __forceinline__ float bf2f(short h) {
    return __uint_as_float(((unsigned)(unsigned short)h) << 16);
}
__device__ __forceinline__ int swz(int u) { return u ^ ((u >> 5) & 7); }

__global__ void init_ws_kernel(unsigned* ws) { ws[0] = 0u; }

// Split W into bf16 hi/lo, stored in MFMA B-fragment order:
// frag fi = g*4+sub (g=f/32 group; sub 0,1 = cos f halves, sub 2,3 = sin),
// unit index = (fi*16+ks)*64 + lane, holding B[n=lane&15][k=ks*32+(lane>>4)*8+j]
__global__ __launch_bounds__(256) void wconv_kernel(
    const float* __restrict__ kr, const float* __restrict__ ki,
    float* __restrict__ w256, short* __restrict__ whi, short* __restrict__ wlo)
{
    const int tid  = threadIdx.x;
    const int pair = blockIdx.x * 4 + (tid >> 6);   // (fi,ks) in [0,512)
    const int lane = tid & 63;
    const int fi = pair >> 4, ks = pair & 15;
    const int g = fi >> 2, sub = fi & 3;
    const float* src = (sub & 2) ? ki : kr;
    const int f  = g * 32 + (sub & 1) * 16 + (lane & 15);
    const int k0 = ks * 32 + (lane >> 4) * 8;
    bf16x8 h8, l8;
    #pragma unroll
    for (int j = 0; j < 8; ++j) {
        float w = src[(k0 + j) * 257 + f];
        short hh = f2bf(w);
        h8[j] = hh;
        l8[j] = f2bf(w - bf2f(hh));
    }
    const int off = ((fi * 16 + ks) * 64 + lane) * 8;
    *(bf16x8*)(whi + off) = h8;
    *(bf16x8*)(wlo + off) = l8;
    if (blockIdx.x == 0) {       // Nyquist weights (f=256): kr[d*257+256]
        w256[tid]       = kr[tid * 257 + 256];
        w256[tid + 256] = kr[(tid + 256) * 257 + 256];
    }
}

// One block: 16 frames x 2 channels (32 M-rows) x 128 filters (cos+sin = 256 n').
// 4 waves, wave w handles filter group g = ft*4+w (32 filters: nf 0,1 cos / 2,3 sin).
__global__ __launch_bounds__(256) void spec_kernel(
    const float* __restrict__ x,
    const short* __restrict__ whi, const short* __restrict__ wlo,
    const float* __restrict__ w256,
    float* __restrict__ out, unsigned* __restrict__ wsmax)
{
    __shared__ short Ah[2 * UNITS_CH * 8];
    __shared__ short Al[2 * UNITS_CH * 8];
    __shared__ float psum[128];
    __shared__ float wmax[4];

    const int blk = blockIdx.x;
    const int ft  = blk & 1;            // filter half
    const int tt  = (blk >> 1) & 63;    // t-tile
    const int b   = blk >> 7;
    const int tid = threadIdx.x;
    const int lane = tid & 63;
    const int wv   = tid >> 6;
    const int col  = lane & 15;
    const int quad = lane >> 4;

    // ---- stage A: 4352 samples/channel -> bf16 hi/lo, swizzled 16B units ----
    const int s_origin = tt * 4096 - 128;
    const bool interior = (tt > 0) && (tt < 63);
    for (int U = tid; U < 2 * UNITS_CH; U += 256) {
        const int ch = (U >= UNITS_CH) ? 1 : 0;
        const int u  = U - ch * UNITS_CH;
        const int g0 = s_origin + u * 8;
        const float* xp = x + ((size_t)b * 2 + ch) * L_IN;
        float v[8];
        if (interior) {
            float4 p0 = *(const float4*)(xp + g0);
            float4 p1 = *(const float4*)(xp + g0 + 4);
            v[0]=p0.x; v[1]=p0.y; v[2]=p0.z; v[3]=p0.w;
            v[4]=p1.x; v[5]=p1.y; v[6]=p1.z; v[7]=p1.w;
        } else {
            #pragma unroll
            for (int j = 0; j < 8; ++j) {
                const int idx = g0 + j;
                v[j] = (idx >= 0 && idx < L_IN) ? xp[idx] : 0.0f;
            }
        }
        bf16x8 h8, l8;
        #pragma unroll
        for (int j = 0; j < 8; ++j) {
            short hh = f2bf(v[j]);
            h8[j] = hh;
            l8[j] = f2bf(v[j] - bf2f(hh));
        }
        const int su = swz(u);
        *(bf16x8*)&Ah[(ch * UNITS_CH + su) * 8] = h8;
        *(bf16x8*)&Al[(ch * UNITS_CH + su) * 8] = l8;
    }
    __syncthreads();

    // ---- K loop: no barriers, B streamed from L2-resident frag-ordered ws ----
    f32x4 acc[2][4];
    const f32x4 zz = {0.0f, 0.0f, 0.0f, 0.0f};
    #pragma unroll
    for (int mf = 0; mf < 2; ++mf)
        #pragma unroll
        for (int nf = 0; nf < 4; ++nf) acc[mf][nf] = zz;

    const int g = ft * 4 + wv;
    for (int ks = 0; ks < 16; ++ks) {
        const int k8 = ks * 4 + quad;
        const int su = swz(col * 32 + k8);
        const bf16x8 a0h = *(const bf16x8*)&Ah[su * 8];
        const bf16x8 a0l = *(const bf16x8*)&Al[su * 8];
        const bf16x8 a1h = *(const bf16x8*)&Ah[(UNITS_CH + su) * 8];
        const bf16x8 a1l = *(const bf16x8*)&Al[(UNITS_CH + su) * 8];
        #pragma unroll
        for (int nf = 0; nf < 4; ++nf) {
            const int off = (((g * 4 + nf) * 16 + ks) * 64 + lane) * 8;
            const bf16x8 bh = *(const bf16x8*)(whi + off);
            const bf16x8 bl = *(const bf16x8*)(wlo + off);
            acc[0][nf] = __builtin_amdgcn_mfma_f32_16x16x32_bf16(a0h, bh, acc[0][nf], 0, 0, 0);
            acc[0][nf] = __builtin_amdgcn_mfma_f32_16x16x32_bf16(a0l, bh, acc[0][nf], 0, 0, 0);
            acc[0][nf] = __builtin_amdgcn_mfma_f32_16x16x32_bf16(a0h, bl, acc[0][nf], 0, 0, 0);
            acc[1][nf] = __builtin_amdgcn_mfma_f32_16x16x32_bf16(a1h, bh, acc[1][nf], 0, 0, 0);
            acc[1][nf] = __builtin_amdgcn_mfma_f32_16x16x32_bf16(a1l, bh, acc[1][nf], 0, 0, 0);
            acc[1][nf] = __builtin_amdgcn_mfma_f32_16x16x32_bf16(a1h, bl, acc[1][nf], 0, 0, 0);
        }
    }

    // ---- Nyquist (f=256) partials from LDS, ft==1 blocks only ----
    if (ft && tid < 128) {
        const int m = tid & 31, kc = tid >> 5;
        const int c = m >> 4, fm = m & 15;
        float s = 0.0f;
        for (int d = kc * 128; d < kc * 128 + 128; ++d) {
            const int ss = fm * 256 + d;
            const int e  = (c * UNITS_CH + swz(ss >> 3)) * 8 + (ss & 7);
            s += (bf2f(Ah[e]) + bf2f(Al[e])) * w256[d];
        }
        psum[tid] = s;
    }

    // ---- epilogue: p = re^2+im^2, store, track max ----
    float pmax = 0.0f;
    #pragma unroll
    for (int mf = 0; mf < 2; ++mf) {           // mf = channel
        #pragma unroll
        for (int nfp = 0; nfp < 2; ++nfp) {
            const int f = g * 32 + nfp * 16 + col;
            #pragma unroll
            for (int r = 0; r < 4; ++r) {
                const float re = acc[mf][nfp][r];
                const float im = acc[mf][nfp + 2][r];
                float p = fmaxf(re * re + im * im, AMIN);
                pmax = fmaxf(pmax, p);
                const int t = tt * 16 + quad * 4 + r;
                out[(((size_t)b * 257 + f) * N_FRAME + t) * 2 + mf] = p;
            }
        }
    }

    __syncthreads();
    if (ft && tid < 32) {
        const float r = psum[tid] + psum[32 + tid] + psum[64 + tid] + psum[96 + tid];
        const float p = fmaxf(r * r, AMIN);
        const int c = tid >> 4, fm = tid & 15;
        out[(((size_t)b * 257 + 256) * N_FRAME + tt * 16 + fm) * 2 + c] = p;
        pmax = fmaxf(pmax, p);
    }

    #pragma unroll
    for (int off = 32; off > 0; off >>= 1)
        pmax = fmaxf(pmax, __shfl_down(pmax, off, 64));
    if (lane == 0) wmax[wv] = pmax;
    __syncthreads();
    if (tid == 0) {
        const float m2 = fmaxf(fmaxf(wmax[0], wmax[1]), fmaxf(wmax[2], wmax[3]));
        atomicMax(wsmax, __float_as_uint(m2));
    }
}

__global__ __launch_bounds__(256) void finalize_kernel(
    float* __restrict__ out, const unsigned* __restrict__ ws_max, int n4)
{
    const int i = blockIdx.x * 256 + threadIdx.x;
    if (i >= n4) return;
    const float mlog = 10.0f * log10f(__uint_as_float(*ws_max));
    float4 p = ((const float4*)out)[i];
    float4 v;
    v.x = fmaxf(10.0f * log10f(p.x) - mlog, -DRANGE);
    v.y = fmaxf(10.0f * log10f(p.y) - mlog, -DRANGE);
    v.z = fmaxf(10.0f * log10f(p.z) - mlog, -DRANGE);
    v.w = fmaxf(10.0f * log10f(p.w) - mlog, -DRANGE);
    ((float4*)out)[i] = v;
}

extern "C" void kernel_launch(void* const* d_in, const int* in_sizes, int n_in,
                              void* d_out, int out_size, void* d_ws, size_t ws_size,
                              hipStream_t stream) {
    const float* x  = (const float*)d_in[0];
    const float* kr = (const float*)d_in[1];
    const float* ki = (const float*)d_in[2];
    float* out      = (float*)d_out;

    unsigned* wsmax = (unsigned*)d_ws;
    float* w256     = (float*)((char*)d_ws + WS_W256_OFF);
    short* whi      = (short*)((char*)d_ws + WS_HI_OFF);
    short* wlo      = (short*)((char*)d_ws + WS_HI_OFF + WS_HALF);

    init_ws_kernel<<<1, 1, 0, stream>>>(wsmax);
    wconv_kernel<<<128, 256, 0, stream>>>(kr, ki, w256, whi, wlo);

    const int nblocks = 32 * 64 * 2;   // b * t-tiles * filter-halves
    spec_kernel<<<nblocks, 256, 0, stream>>>(x, whi, wlo, w256, out, wsmax);

    const int n4 = out_size / 4;
    finalize_kernel<<<(n4 + 255) / 256, 256, 0, stream>>>(out, wsmax, n4);
}

// Round 3
// 247.450 us; speedup vs baseline: 3.7943x; 1.2074x over previous
//
#include <hip/hip_runtime.h>
#include <math.h>

#define L_IN     262144
#define N_FRAME  1024
#define AMIN     1e-10f
#define DRANGE   80.0f
#define UNITS_CH 1056            // (32*256+256)/8 16B-units per channel
#define WS_HI_OFF   4096
#define WS_HALF     540672       // 33 frags * 16 ks * 64 lanes * 16B

typedef short bf16x8 __attribute__((ext_vector_type(8)));
typedef float f32x4  __attribute__((ext_vector_type(4)));

__device__ __forceinline__ short f2bf(float f) {           // fp32 -> bf16 RNE
    unsigned u = __float_as_uint(f);
    u = (u + 0x7FFFu + ((u >> 16) & 1u)) >> 16;
    return (short)u;
}
__device__ __forceinline__ float bf2f(short h) {
    return __uint_as_float(((unsigned)(unsigned short)h) << 16);
}
__device__ __forceinline__ int swz(int u) { return u ^ ((u >> 5) & 7); }

__global__ void init_ws_kernel(unsigned* ws) { ws[0] = 0u; }

// W -> bf16 hi/lo in MFMA B-fragment order.
// frag fi in [0,33): fi<32: g=fi>>2, sub=fi&3 (0,1=cos halves, 2,3=sin);
// fi==32: Nyquist column (f=256 cos weights in n==0, zeros elsewhere).
// unit (fi*16+ks)*64+lane holds B[n=lane&15][k=ks*32+(lane>>4)*8+j]
__global__ __launch_bounds__(256) void wconv_kernel(
    const float* __restrict__ kr, const float* __restrict__ ki,
    short* __restrict__ whi, short* __restrict__ wlo)
{
    const int tid  = threadIdx.x;
    const int pair = blockIdx.x * 4 + (tid >> 6);   // (fi,ks) in [0,528)
    const int lane = tid & 63;
    const int fi = pair >> 4, ks = pair & 15;
    const int n  = lane & 15;
    const int k0 = ks * 32 + (lane >> 4) * 8;
    bf16x8 h8, l8;
    if (fi < 32) {
        const int g = fi >> 2, sub = fi & 3;
        const float* src = (sub & 2) ? ki : kr;
        const int f = g * 32 + (sub & 1) * 16 + n;
        #pragma unroll
        for (int j = 0; j < 8; ++j) {
            float w = src[(k0 + j) * 257 + f];
            short hh = f2bf(w);
            h8[j] = hh;
            l8[j] = f2bf(w - bf2f(hh));
        }
    } else {                                        // Nyquist frag
        #pragma unroll
        for (int j = 0; j < 8; ++j) {
            float w = (n == 0) ? kr[(k0 + j) * 257 + 256] : 0.0f;
            short hh = f2bf(w);
            h8[j] = hh;
            l8[j] = f2bf(w - bf2f(hh));
        }
    }
    const int off = ((fi * 16 + ks) * 64 + lane) * 8;
    *(bf16x8*)(whi + off) = h8;
    *(bf16x8*)(wlo + off) = l8;
}

// One block: 32 frames x 2 channels (M=64 rows) x 128 filters (cos+sin).
// 4 waves; wave wv owns filter group g = ft*4+wv; acc = 4 M-frags x 4 N-frags.
__global__ __launch_bounds__(256, 2) void spec_kernel(
    const float* __restrict__ x,
    const short* __restrict__ whi, const short* __restrict__ wlo,
    float* __restrict__ out, unsigned* __restrict__ wsmax)
{
    __shared__ short Ah[2 * UNITS_CH * 8];   // 67.6 KB
    __shared__ short Al[2 * UNITS_CH * 8];   // 67.6 KB
    __shared__ float wmax[4];

    const int blk = blockIdx.x;
    const int ft  = blk & 1;
    const int tt  = (blk >> 1) & 31;        // 32-frame t-tile
    const int b   = blk >> 6;
    const int tid = threadIdx.x;
    const int lane = tid & 63;
    const int wv   = tid >> 6;
    const int col  = lane & 15;
    const int quad = lane >> 4;

    // ---- stage A: 8448 samples/channel -> bf16 hi/lo, swizzled 16B units ----
    const int s_origin = tt * 8192 - 128;
    const bool interior = (tt > 0) && (tt < 31);
    for (int U = tid; U < 2 * UNITS_CH; U += 256) {
        const int ch = (U >= UNITS_CH) ? 1 : 0;
        const int u  = U - ch * UNITS_CH;
        const int g0 = s_origin + u * 8;
        const float* xp = x + ((size_t)b * 2 + ch) * L_IN;
        float v[8];
        if (interior) {
            float4 p0 = *(const float4*)(xp + g0);
            float4 p1 = *(const float4*)(xp + g0 + 4);
            v[0]=p0.x; v[1]=p0.y; v[2]=p0.z; v[3]=p0.w;
            v[4]=p1.x; v[5]=p1.y; v[6]=p1.z; v[7]=p1.w;
        } else {
            #pragma unroll
            for (int j = 0; j < 8; ++j) {
                const int idx = g0 + j;
                v[j] = (idx >= 0 && idx < L_IN) ? xp[idx] : 0.0f;
            }
        }
        bf16x8 h8, l8;
        #pragma unroll
        for (int j = 0; j < 8; ++j) {
            short hh = f2bf(v[j]);
            h8[j] = hh;
            l8[j] = f2bf(v[j] - bf2f(hh));
        }
        const int su = swz(u);
        *(bf16x8*)&Ah[(ch * UNITS_CH + su) * 8] = h8;
        *(bf16x8*)&Al[(ch * UNITS_CH + su) * 8] = l8;
    }
    __syncthreads();

    // ---- K loop: barrier-free; B streamed from L2 with register dbuf ----
    const int g = ft * 4 + wv;
    const bool ny = (ft == 1) && (wv == 3);
    const int laneoff = lane * 8;

    f32x4 acc[4][4];
    f32x4 accN[4];
    const f32x4 zz = {0.0f, 0.0f, 0.0f, 0.0f};
    #pragma unroll
    for (int mf = 0; mf < 4; ++mf) {
        accN[mf] = zz;
        #pragma unroll
        for (int nf = 0; nf < 4; ++nf) acc[mf][nf] = zz;
    }

    bf16x8 bh[4], bl[4], nyh, nyl;
    #pragma unroll
    for (int nf = 0; nf < 4; ++nf) {
        const int off = ((g * 4 + nf) * 16) * 512 + laneoff;
        bh[nf] = *(const bf16x8*)(whi + off);
        bl[nf] = *(const bf16x8*)(wlo + off);
    }
    if (ny) {
        const int off = (32 * 16) * 512 + laneoff;
        nyh = *(const bf16x8*)(whi + off);
        nyl = *(const bf16x8*)(wlo + off);
    }

    for (int ks = 0; ks < 16; ++ks) {
        const int k8 = ks * 4 + quad;
        bf16x8 ah[4], al[4];
        #pragma unroll
        for (int mf = 0; mf < 4; ++mf) {
            const int fr = (mf & 1) * 16 + col;
            const int su = (mf >> 1) * UNITS_CH + swz(fr * 32 + k8);
            ah[mf] = *(const bf16x8*)&Ah[su * 8];
            al[mf] = *(const bf16x8*)&Al[su * 8];
        }
        bf16x8 nbh[4], nbl[4], nnyh, nnyl;
        if (ks < 15) {
            #pragma unroll
            for (int nf = 0; nf < 4; ++nf) {
                const int off = (((g * 4 + nf) * 16) + ks + 1) * 512 + laneoff;
                nbh[nf] = *(const bf16x8*)(whi + off);
                nbl[nf] = *(const bf16x8*)(wlo + off);
            }
            if (ny) {
                const int off = ((32 * 16) + ks + 1) * 512 + laneoff;
                nnyh = *(const bf16x8*)(whi + off);
                nnyl = *(const bf16x8*)(wlo + off);
            }
        }
        #pragma unroll
        for (int nf = 0; nf < 4; ++nf)
            #pragma unroll
            for (int mf = 0; mf < 4; ++mf) {
                acc[mf][nf] = __builtin_amdgcn_mfma_f32_16x16x32_bf16(ah[mf], bh[nf], acc[mf][nf], 0, 0, 0);
                acc[mf][nf] = __builtin_amdgcn_mfma_f32_16x16x32_bf16(al[mf], bh[nf], acc[mf][nf], 0, 0, 0);
                acc[mf][nf] = __builtin_amdgcn_mfma_f32_16x16x32_bf16(ah[mf], bl[nf], acc[mf][nf], 0, 0, 0);
            }
        if (ny) {
            #pragma unroll
            for (int mf = 0; mf < 4; ++mf) {
                accN[mf] = __builtin_amdgcn_mfma_f32_16x16x32_bf16(ah[mf], nyh, accN[mf], 0, 0, 0);
                accN[mf] = __builtin_amdgcn_mfma_f32_16x16x32_bf16(al[mf], nyh, accN[mf], 0, 0, 0);
                accN[mf] = __builtin_amdgcn_mfma_f32_16x16x32_bf16(ah[mf], nyl, accN[mf], 0, 0, 0);
            }
        }
        #pragma unroll
        for (int nf = 0; nf < 4; ++nf) { bh[nf] = nbh[nf]; bl[nf] = nbl[nf]; }
        if (ny) { nyh = nnyh; nyl = nnyl; }
    }

    // ---- epilogue ----
    float pmax = 0.0f;
    #pragma unroll
    for (int mf = 0; mf < 4; ++mf) {
        const int ch = mf >> 1;
        const int tbase = tt * 32 + (mf & 1) * 16 + quad * 4;
        #pragma unroll
        for (int nfp = 0; nfp < 2; ++nfp) {
            const int f = g * 32 + nfp * 16 + col;
            #pragma unroll
            for (int r = 0; r < 4; ++r) {
                const float re = acc[mf][nfp][r];
                const float im = acc[mf][nfp + 2][r];
                float p = fmaxf(re * re + im * im, AMIN);
                pmax = fmaxf(pmax, p);
                out[(((size_t)b * 257 + f) * N_FRAME + (tbase + r)) * 2 + ch] = p;
            }
        }
    }
    if (ny && col == 0) {
        #pragma unroll
        for (int mf = 0; mf < 4; ++mf) {
            const int ch = mf >> 1;
            const int tbase = tt * 32 + (mf & 1) * 16 + quad * 4;
            #pragma unroll
            for (int r = 0; r < 4; ++r) {
                const float re = accN[mf][r];
                float p = fmaxf(re * re, AMIN);
                pmax = fmaxf(pmax, p);
                out[(((size_t)b * 257 + 256) * N_FRAME + (tbase + r)) * 2 + ch] = p;
            }
        }
    }

    #pragma unroll
    for (int off = 32; off > 0; off >>= 1)
        pmax = fmaxf(pmax, __shfl_down(pmax, off, 64));
    if (lane == 0) wmax[wv] = pmax;
    __syncthreads();
    if (tid == 0) {
        const float m2 = fmaxf(fmaxf(wmax[0], wmax[1]), fmaxf(wmax[2], wmax[3]));
        atomicMax(wsmax, __float_as_uint(m2));
    }
}

__global__ __launch_bounds__(256) void finalize_kernel(
    float* __restrict__ out, const unsigned* __restrict__ ws_max, int n4)
{
    const int i = blockIdx.x * 256 + threadIdx.x;
    if (i >= n4) return;
    const float mlog = 10.0f * log10f(__uint_as_float(*ws_max));
    float4 p = ((const float4*)out)[i];
    float4 v;
    v.x = fmaxf(10.0f * log10f(p.x) - mlog, -DRANGE);
    v.y = fmaxf(10.0f * log10f(p.y) - mlog, -DRANGE);
    v.z = fmaxf(10.0f * log10f(p.z) - mlog, -DRANGE);
    v.w = fmaxf(10.0f * log10f(p.w) - mlog, -DRANGE);
    ((float4*)out)[i] = v;
}

extern "C" void kernel_launch(void* const* d_in, const int* in_sizes, int n_in,
                              void* d_out, int out_size, void* d_ws, size_t ws_size,
                              hipStream_t stream) {
    const float* x  = (const float*)d_in[0];
    const float* kr = (const float*)d_in[1];
    const float* ki = (const float*)d_in[2];
    float* out      = (float*)d_out;

    unsigned* wsmax = (unsigned*)d_ws;
    short* whi      = (short*)((char*)d_ws + WS_HI_OFF);
    short* wlo      = (short*)((char*)d_ws + WS_HI_OFF + WS_HALF);

    init_ws_kernel<<<1, 1, 0, stream>>>(wsmax);
    wconv_kernel<<<132, 256, 0, stream>>>(kr, ki, whi, wlo);

    const int nblocks = 32 * 32 * 2;   // b * t-tiles * filter-halves
    spec_kernel<<<nblocks, 256, 0, stream>>>(x, whi, wlo, out, wsmax);

    const int n4 = out_size / 4;
    finalize_kernel<<<(n4 + 255) / 256, 256, 0, stream>>>(out, wsmax, n4);
}

// Round 4
// 240.645 us; speedup vs baseline: 3.9016x; 1.0283x over previous
//
#include <hip/hip_runtime.h>
#include <math.h>

#define L_IN     262144
#define N_FRAME  1024
#define AMIN     1e-10f
#define DRANGE   80.0f
#define UNITS_CH 1056            // (32 frames * 256 hop + 256)/8 16B-units per channel
#define WS_HI_OFF   4096
#define WS_HALF     524288       // 16 frags * 32 kk * 64 lanes * 16B

typedef short bf16x8 __attribute__((ext_vector_type(8)));
typedef float f32x16 __attribute__((ext_vector_type(16)));

__device__ __forceinline__ short f2bf(float f) {           // fp32 -> bf16 RNE
    unsigned u = __float_as_uint(f);
    u = (u + 0x7FFFu + ((u >> 16) & 1u)) >> 16;
    return (short)u;
}
__device__ __forceinline__ float bf2f(short h) {
    return __uint_as_float(((unsigned)(unsigned short)h) << 16);
}
__device__ __forceinline__ int swz(int u) { return u ^ ((u >> 5) & 7); }

// W -> bf16 hi/lo in 32x32x16 MFMA B-frag order.
// frag fi = g*2+nf (g = filter group of 32, nf: 0=cos, 1=sin).
// unit ((fi*32+kk)*64+lane)*16B holds B[n=lane&31][k=kk*16+(lane>>5)*8+j].
// Special: fi==1 (g0 sin), n==0 column is filter-0 sin == all zeros -> holds
// the Nyquist (f=256) cos weights instead.
__global__ __launch_bounds__(256) void wconv_kernel(
    const float* __restrict__ kr, const float* __restrict__ ki,
    short* __restrict__ whi, short* __restrict__ wlo, unsigned* __restrict__ wsmax)
{
    if (blockIdx.x == 0 && threadIdx.x == 0) wsmax[0] = 0u;
    const int tid  = threadIdx.x;
    const int pair = blockIdx.x * 4 + (tid >> 6);   // (fi,kk) in [0,512)
    const int lane = tid & 63;
    const int fi = pair >> 5, kk = pair & 31;
    const int g = fi >> 1, nf = fi & 1;
    const int n  = lane & 31;
    const int k0 = kk * 16 + (lane >> 5) * 8;
    const int f  = g * 32 + n;
    bf16x8 h8, l8;
    #pragma unroll
    for (int j = 0; j < 8; ++j) {
        const int k = k0 + j;
        float w;
        if (nf == 1 && g == 0 && n == 0) w = kr[k * 257 + 256];   // Nyquist column
        else                             w = (nf ? ki : kr)[k * 257 + f];
        short hh = f2bf(w);
        h8[j] = hh;
        l8[j] = f2bf(w - bf2f(hh));
    }
    const int off = ((fi * 32 + kk) * 64 + lane) * 8;
    *(bf16x8*)(whi + off) = h8;
    *(bf16x8*)(wlo + off) = l8;
}

// One block: 32 frames x 2 channels (M=64, frag mf = channel) x all 257 filters.
// 8 waves; wave wv owns filter group g=wv (32 filters, nf0=cos frag, nf1=sin frag).
__global__ __launch_bounds__(512) void spec_kernel(
    const float* __restrict__ x,
    const short* __restrict__ whi, const short* __restrict__ wlo,
    float* __restrict__ out, unsigned* __restrict__ wsmax)
{
    __shared__ short Ah[2 * UNITS_CH * 8];   // 33.8 KB
    __shared__ short Al[2 * UNITS_CH * 8];   // 33.8 KB
    __shared__ float wmax[8];

    const int blk = blockIdx.x;
    const int tt  = blk & 31;
    const int b   = blk >> 5;
    const int tid = threadIdx.x;
    const int lane = tid & 63;
    const int g    = tid >> 6;          // wave = filter group
    const int col  = lane & 31;
    const int half = lane >> 5;

    // ---- stage A: 8448 samples/channel -> bf16 hi/lo, swizzled 16B units ----
    const int s_origin = tt * 8192 - 128;
    const bool interior = (tt > 0) && (tt < 31);
    for (int U = tid; U < 2 * UNITS_CH; U += 512) {
        const int ch = (U >= UNITS_CH) ? 1 : 0;
        const int u  = U - ch * UNITS_CH;
        const int g0 = s_origin + u * 8;
        const float* xp = x + ((size_t)b * 2 + ch) * L_IN;
        float v[8];
        if (interior) {
            float4 p0 = *(const float4*)(xp + g0);
            float4 p1 = *(const float4*)(xp + g0 + 4);
            v[0]=p0.x; v[1]=p0.y; v[2]=p0.z; v[3]=p0.w;
            v[4]=p1.x; v[5]=p1.y; v[6]=p1.z; v[7]=p1.w;
        } else {
            #pragma unroll
            for (int j = 0; j < 8; ++j) {
                const int idx = g0 + j;
                v[j] = (idx >= 0 && idx < L_IN) ? xp[idx] : 0.0f;
            }
        }
        bf16x8 h8, l8;
        #pragma unroll
        for (int j = 0; j < 8; ++j) {
            short hh = f2bf(v[j]);
            h8[j] = hh;
            l8[j] = f2bf(v[j] - bf2f(hh));
        }
        const int su = swz(u);
        *(bf16x8*)&Ah[(ch * UNITS_CH + su) * 8] = h8;
        *(bf16x8*)&Al[(ch * UNITS_CH + su) * 8] = l8;
    }
    __syncthreads();

    // ---- K loop: barrier-free; B streamed from L2 with register dbuf ----
    f32x16 acc[2][2];
    #pragma unroll
    for (int mf = 0; mf < 2; ++mf)
        #pragma unroll
        for (int nf = 0; nf < 2; ++nf)
            #pragma unroll
            for (int r = 0; r < 16; ++r) acc[mf][nf][r] = 0.0f;

    const int laneoff = lane * 8;
    bf16x8 bh[2][2], bl[2][2];
    #pragma unroll
    for (int nf = 0; nf < 2; ++nf)
        #pragma unroll
        for (int kh = 0; kh < 2; ++kh) {
            const int off = (((g * 2 + nf) * 32 + kh) * 64) * 8 + laneoff;
            bh[nf][kh] = *(const bf16x8*)(whi + off);
            bl[nf][kh] = *(const bf16x8*)(wlo + off);
        }

    for (int kp = 0; kp < 16; ++kp) {
        bf16x8 ah[2][2], al[2][2];
        #pragma unroll
        for (int mf = 0; mf < 2; ++mf)
            #pragma unroll
            for (int kh = 0; kh < 2; ++kh) {
                const int u = col * 32 + kp * 4 + kh * 2 + half;
                const int e = (mf * UNITS_CH + swz(u)) * 8;
                ah[mf][kh] = *(const bf16x8*)&Ah[e];
                al[mf][kh] = *(const bf16x8*)&Al[e];
            }
        bf16x8 nbh[2][2], nbl[2][2];
        if (kp < 15) {
            #pragma unroll
            for (int nf = 0; nf < 2; ++nf)
                #pragma unroll
                for (int kh = 0; kh < 2; ++kh) {
                    const int off = (((g * 2 + nf) * 32 + (kp + 1) * 2 + kh) * 64) * 8 + laneoff;
                    nbh[nf][kh] = *(const bf16x8*)(whi + off);
                    nbl[nf][kh] = *(const bf16x8*)(wlo + off);
                }
        }
        // pass-major: hh, lh, hl — same-acc dependents >= 4 apart
        #pragma unroll
        for (int kh = 0; kh < 2; ++kh)
            #pragma unroll
            for (int mf = 0; mf < 2; ++mf)
                #pragma unroll
                for (int nf = 0; nf < 2; ++nf)
                    acc[mf][nf] = __builtin_amdgcn_mfma_f32_32x32x16_bf16(ah[mf][kh], bh[nf][kh], acc[mf][nf], 0, 0, 0);
        #pragma unroll
        for (int kh = 0; kh < 2; ++kh)
            #pragma unroll
            for (int mf = 0; mf < 2; ++mf)
                #pragma unroll
                for (int nf = 0; nf < 2; ++nf)
                    acc[mf][nf] = __builtin_amdgcn_mfma_f32_32x32x16_bf16(al[mf][kh], bh[nf][kh], acc[mf][nf], 0, 0, 0);
        #pragma unroll
        for (int kh = 0; kh < 2; ++kh)
            #pragma unroll
            for (int mf = 0; mf < 2; ++mf)
                #pragma unroll
                for (int nf = 0; nf < 2; ++nf)
                    acc[mf][nf] = __builtin_amdgcn_mfma_f32_32x32x16_bf16(ah[mf][kh], bl[nf][kh], acc[mf][nf], 0, 0, 0);
        #pragma unroll
        for (int nf = 0; nf < 2; ++nf)
            #pragma unroll
            for (int kh = 0; kh < 2; ++kh) {
                bh[nf][kh] = nbh[nf][kh]; bl[nf][kh] = nbl[nf][kh];
            }
    }

    // ---- epilogue: p = re^2+im^2, store, track max ----
    // C/D layout (32x32): n = lane&31, m = (r&3) + 8*(r>>2) + 4*(lane>>5)
    const bool nyq = (g == 0) && (col == 0);
    float pmax = 0.0f;
    #pragma unroll
    for (int mf = 0; mf < 2; ++mf) {          // mf = channel
        const int f = g * 32 + col;
        #pragma unroll
        for (int r = 0; r < 16; ++r) {
            const int m = (r & 3) + 8 * (r >> 2) + 4 * half;
            const int t = tt * 32 + m;
            const float re = acc[mf][0][r];
            const float im = acc[mf][1][r];
            const float imq = nyq ? 0.0f : im;
            float p = fmaxf(re * re + imq * imq, AMIN);
            pmax = fmaxf(pmax, p);
            out[(((size_t)b * 257 + f) * N_FRAME + t) * 2 + mf] = p;
            if (nyq) {                         // sin-frag col0 carries f=256 re
                float pn = fmaxf(im * im, AMIN);
                pmax = fmaxf(pmax, pn);
                out[(((size_t)b * 257 + 256) * N_FRAME + t) * 2 + mf] = pn;
            }
        }
    }

    #pragma unroll
    for (int off = 32; off > 0; off >>= 1)
        pmax = fmaxf(pmax, __shfl_down(pmax, off, 64));
    if (lane == 0) wmax[g] = pmax;
    __syncthreads();
    if (tid == 0) {
        float m2 = wmax[0];
        #pragma unroll
        for (int w = 1; w < 8; ++w) m2 = fmaxf(m2, wmax[w]);
        atomicMax(wsmax, __float_as_uint(m2));
    }
}

__global__ __launch_bounds__(256) void finalize_kernel(
    float* __restrict__ out, const unsigned* __restrict__ ws_max, int n4)
{
    const int i = blockIdx.x * 256 + threadIdx.x;
    if (i >= n4) return;
    const float mlog = 10.0f * log10f(__uint_as_float(*ws_max));
    float4 p = ((const float4*)out)[i];
    float4 v;
    v.x = fmaxf(10.0f * log10f(p.x) - mlog, -DRANGE);
    v.y = fmaxf(10.0f * log10f(p.y) - mlog, -DRANGE);
    v.z = fmaxf(10.0f * log10f(p.z) - mlog, -DRANGE);
    v.w = fmaxf(10.0f * log10f(p.w) - mlog, -DRANGE);
    ((float4*)out)[i] = v;
}

extern "C" void kernel_launch(void* const* d_in, const int* in_sizes, int n_in,
                              void* d_out, int out_size, void* d_ws, size_t ws_size,
                              hipStream_t stream) {
    const float* x  = (const float*)d_in[0];
    const float* kr = (const float*)d_in[1];
    const float* ki = (const float*)d_in[2];
    float* out      = (float*)d_out;

    unsigned* wsmax = (unsigned*)d_ws;
    short* whi      = (short*)((char*)d_ws + WS_HI_OFF);
    short* wlo      = (short*)((char*)d_ws + WS_HI_OFF + WS_HALF);

    wconv_kernel<<<128, 256, 0, stream>>>(kr, ki, whi, wlo, wsmax);

    const int nblocks = 32 * 32;       // b * t-tiles
    spec_kernel<<<nblocks, 512, 0, stream>>>(x, whi, wlo, out, wsmax);

    const int n4 = out_size / 4;
    finalize_kernel<<<(n4 + 255) / 256, 256, 0, stream>>>(out, wsmax, n4);
}